// Round 5
// baseline (535.636 us; speedup 1.0000x reference)
//
#include <hip/hip_runtime.h>
#include <math.h>

// Dims fixed: T=4, B=8, C=128, H=W=56, mid=128.
#define T_ 4
#define B_ 8
#define C_ 128
#define H_ 56
#define W_ 56
#define NIMG (T_ * B_)              // 32
#define HW (H_ * W_)                // 3136
#define NLOC ((size_t)B_ * C_ * HW) // 3211264 per-t elements
#define NE ((size_t)T_ * NLOC)      // 12845056

typedef __attribute__((ext_vector_type(4))) int   int4v;
typedef __attribute__((ext_vector_type(4))) float float4v;

#define GLOAD_LDS16(gp, lp) \
    __builtin_amdgcn_global_load_lds((const __attribute__((address_space(1))) unsigned int*)(gp), \
                                     (__attribute__((address_space(3))) unsigned int*)(lp), 16, 0, 0)

// ---------------------------------------------------------------------------
// per-co scale: sv[co] = max_{ci,tap}|w[co][ci][tap]| / 127
// ---------------------------------------------------------------------------
__global__ __launch_bounds__(128) void scale_k(const float* __restrict__ w,
                                               float* __restrict__ sv) {
    __shared__ float red[128];
    int co = blockIdx.x, t = threadIdx.x;
    const float* p = w + (size_t)co * 1152 + t * 9;
    float m = 0.f;
#pragma unroll
    for (int j = 0; j < 9; ++j) m = fmaxf(m, fabsf(p[j]));
    red[t] = m; __syncthreads();
    for (int off = 64; off; off >>= 1) {
        if (t < off) red[t] = fmaxf(red[t], red[t + off]);
        __syncthreads();
    }
    if (t == 0) sv[co] = fmaxf(red[0], 1e-20f) / 127.f;
}

// ---------------------------------------------------------------------------
// repack weights -> 27 stages, register-fragment-coalesced layout:
// byte off = stage*16384 + q*4096 + nf*2048 + ks*1024 + fq*256 + fr*16 + i
//   where co = q*32 + nf*16 + fr, ci = (ks*4+fq)*16 + i, stage = tap*3 + split
// 3-way split: w = s*(q1 + q2/128 + q3/16384); |q2|,|q3| <= 64
// ---------------------------------------------------------------------------
__global__ __launch_bounds__(256) void repack_k(const float* __restrict__ w,
                                                const float* __restrict__ sv,
                                                signed char* __restrict__ Bq) {
    int idx = blockIdx.x * 256 + threadIdx.x;
    if (idx >= 9 * 1024) return;
    int tap = idx >> 10;
    int rem = idx & 1023;
    int co = rem >> 3, chunk = rem & 7;
    int ks = chunk >> 2, fq = chunk & 3;
    int q = co >> 5, fr = co & 15, nf = (co >> 4) & 1;
    double s = (double)sv[co];
    union { signed char b[16]; int4v v; } out[3];
#pragma unroll
    for (int e = 0; e < 16; ++e) {
        int ci = chunk * 16 + e;
        double v = (double)w[((size_t)co * 128 + ci) * 9 + tap];
        double q1 = rint(v / s);
        double r1 = v - s * q1;
        double q2 = rint(r1 * 128.0 / s);
        double r2 = r1 - s * q2 * 0.0078125;
        double q3 = rint(r2 * 16384.0 / s);
        out[0].b[e] = (signed char)(int)q1;
        out[1].b[e] = (signed char)(int)q2;
        out[2].b[e] = (signed char)(int)q3;
    }
#pragma unroll
    for (int sp = 0; sp < 3; ++sp) {
        size_t off = (size_t)(tap * 3 + sp) * 16384 + q * 4096 + nf * 2048
                   + ks * 1024 + fq * 256 + fr * 16;
        *(int4v*)(Bq + off) = out[sp].v;
    }
}

// ---------------------------------------------------------------------------
// x fp32 NCHW -> Xt i8 NHWC, ci-slot XOR-swizzled by (w&7):
// byte at px*128 + slot*16 + b holds ci = (slot ^ (px&7))*16 + b
// ---------------------------------------------------------------------------
__global__ __launch_bounds__(256) void xpose_k(const float* __restrict__ x,
                                               signed char* __restrict__ Xt) {
    __shared__ float xs[128][57];
    int n = blockIdx.x / 56, h = blockIdx.x % 56;
    int tid = threadIdx.x;
    const float* xp = x + (size_t)n * 128 * HW + h * 56;
#pragma unroll
    for (int j = 0; j < 7; ++j) {
        int idx = tid + j * 256;              // 0..1791 = c*14 + wq
        int c = idx / 14, wq = idx - c * 14;
        float4 v = *(const float4*)(xp + (size_t)c * HW + wq * 4);
        xs[c][wq * 4 + 0] = v.x; xs[c][wq * 4 + 1] = v.y;
        xs[c][wq * 4 + 2] = v.z; xs[c][wq * 4 + 3] = v.w;
    }
    __syncthreads();
    signed char* Op = Xt + ((size_t)n * HW + h * 56) * 128;
#pragma unroll
    for (int j = 0; j < 2; ++j) {
        int idx = tid + j * 256;              // 0..447 = ww*8 + slot
        if (idx < 448) {
            int ww = idx >> 3, sl = idx & 7;
            int cg = sl ^ (ww & 7);
            union { signed char b[16]; int4v v; } u;
#pragma unroll
            for (int e = 0; e < 16; ++e)
                u.b[e] = (xs[cg * 16 + e][ww] >= 0.5f) ? 1 : 0;
            *(int4v*)(Op + ww * 128 + sl * 16) = u.v;
        }
    }
}

// ---------------------------------------------------------------------------
// conv3x3 SAME + BN, i8 MFMA, barrier-free K-loop, register-dieted.
// Block: 256 thr / 4 waves = 4 co-quarters, one output row, 64px x 32co/wave.
// A (3 rows) in LDS. B per-tap from L2 (12 frags). Accumulators:
//   acc0  = exact int chain for split0 (q1)
//   acc12 = exact int chain for 128*q2 + q3 (folded per (tap,m) from temps)
// ---------------------------------------------------------------------------
__global__ __launch_bounds__(256, 3) void conv_mfma_k(
        const signed char* __restrict__ Xt,   // i8 NHWC swizzled [32][3136][128]
        const signed char* __restrict__ Bq,   // 27 stages x 16KB, frag-coalesced
        const float* __restrict__ sv,
        const float* __restrict__ gamma, const float* __restrict__ beta,
        const float* __restrict__ mean,  const float* __restrict__ var,
        float* __restrict__ Y) {              // fp32 NHWC
    __shared__ signed char aA[3 * 8192];      // rows h-1,h,h+1 x 64px x 128ci

    const int tid = threadIdx.x;
    const int lane = tid & 63;
    const int q = tid >> 6;                   // wave = co-quarter
    const int fr = lane & 15, fq = lane >> 4;
    const int img = blockIdx.x / 56;
    const int h = blockIdx.x % 56;

    // ---- prologue: stage A rows (clamped; masked at use) ----
    const signed char* XtN = Xt + (size_t)img * HW * 128;
#pragma unroll
    for (int i = 0; i < 3; ++i) {
        int hh = h - 1 + i;
        hh = hh < 0 ? 0 : (hh > 55 ? 55 : hh);
        const char* src = (const char*)(XtN + (size_t)hh * 7168);
        GLOAD_LDS16(src + tid * 16, (char*)aA + i * 8192 + tid * 16);
        GLOAD_LDS16(src + 4096 + tid * 16, (char*)aA + i * 8192 + 4096 + tid * 16);
    }
    asm volatile("s_waitcnt vmcnt(0)" ::: "memory");
    __builtin_amdgcn_sched_barrier(0);
    __builtin_amdgcn_s_barrier();              // A ready; no further barriers

    const signed char* bqq = Bq + q * 4096 + fq * 256 + fr * 16;
    const int4v zi = (int4v){0, 0, 0, 0};
    int4v acc0[4][2], acc12[4][2];
#pragma unroll
    for (int m = 0; m < 4; ++m) {
        acc0[m][0] = zi; acc0[m][1] = zi;
        acc12[m][0] = zi; acc12[m][1] = zi;
    }

    // ---- K-loop: 9 taps x (12 B-frag loads + 4m x 12 MFMA + fold) ----
#pragma unroll
    for (int tap = 0; tap < 9; ++tap) {
        const int dh = tap / 3, dw = tap % 3;
        const bool hok = (dh == 1) || (dh == 0 ? (h > 0) : (h < 55));
        int4v bfr[3][2][2];                    // [sp][ks][nf]
#pragma unroll
        for (int sp = 0; sp < 3; ++sp)
#pragma unroll
            for (int ks = 0; ks < 2; ++ks)
#pragma unroll
                for (int nf = 0; nf < 2; ++nf)
                    bfr[sp][ks][nf] = *(const int4v*)(bqq
                        + (size_t)(tap * 3 + sp) * 16384 + nf * 2048 + ks * 1024);
#pragma unroll
        for (int m = 0; m < 4; ++m) {
            int px = m * 16 + fr + dw - 1;
            bool ok = hok && ((unsigned)px < 56u);
            int pxc = ok ? px : 0;
            const signed char* base = aA + dh * 8192 + pxc * 128;
            int4v a0, a1;
            {
                int sl0 = fq ^ (pxc & 7);
                int sl1 = (4 + fq) ^ (pxc & 7);
                int4v v0 = *(const int4v*)(base + sl0 * 16);
                int4v v1 = *(const int4v*)(base + sl1 * 16);
                a0 = ok ? v0 : zi;
                a1 = ok ? v1 : zi;
            }
            // split 0 -> exact chain
            acc0[m][0] = __builtin_amdgcn_mfma_i32_16x16x64_i8(a0, bfr[0][0][0], acc0[m][0], 0, 0, 0);
            acc0[m][0] = __builtin_amdgcn_mfma_i32_16x16x64_i8(a1, bfr[0][1][0], acc0[m][0], 0, 0, 0);
            acc0[m][1] = __builtin_amdgcn_mfma_i32_16x16x64_i8(a0, bfr[0][0][1], acc0[m][1], 0, 0, 0);
            acc0[m][1] = __builtin_amdgcn_mfma_i32_16x16x64_i8(a1, bfr[0][1][1], acc0[m][1], 0, 0, 0);
            // splits 1,2 -> temps, folded exactly: acc12 += (t1<<7) + t2
            int4v t1_0, t1_1, t2_0, t2_1;
            t1_0 = __builtin_amdgcn_mfma_i32_16x16x64_i8(a0, bfr[1][0][0], zi, 0, 0, 0);
            t1_0 = __builtin_amdgcn_mfma_i32_16x16x64_i8(a1, bfr[1][1][0], t1_0, 0, 0, 0);
            t1_1 = __builtin_amdgcn_mfma_i32_16x16x64_i8(a0, bfr[1][0][1], zi, 0, 0, 0);
            t1_1 = __builtin_amdgcn_mfma_i32_16x16x64_i8(a1, bfr[1][1][1], t1_1, 0, 0, 0);
            t2_0 = __builtin_amdgcn_mfma_i32_16x16x64_i8(a0, bfr[2][0][0], zi, 0, 0, 0);
            t2_0 = __builtin_amdgcn_mfma_i32_16x16x64_i8(a1, bfr[2][1][0], t2_0, 0, 0, 0);
            t2_1 = __builtin_amdgcn_mfma_i32_16x16x64_i8(a0, bfr[2][0][1], zi, 0, 0, 0);
            t2_1 = __builtin_amdgcn_mfma_i32_16x16x64_i8(a1, bfr[2][1][1], t2_1, 0, 0, 0);
            acc12[m][0] += (t1_0 << 7) + t2_0;
            acc12[m][1] += (t1_1 << 7) + t2_1;
        }
    }

    // ---- epilogue: fold splits + BN + store ----
    float* Yp = Y + ((size_t)img * HW + h * 56) * 128;
#pragma unroll
    for (int nf = 0; nf < 2; ++nf) {
        int co = q * 32 + nf * 16 + fr;
        float s = sv[co];
        float iv = gamma[co] / sqrtf(var[co] + 1e-5f);
        float mul = s * iv;
        float bs = beta[co] - mean[co] * iv;
#pragma unroll
        for (int m = 0; m < 4; ++m)
#pragma unroll
            for (int r = 0; r < 4; ++r) {
                int ww = m * 16 + fq * 4 + r;
                if (ww < 56) {
                    float val = (float)acc0[m][nf][r]
                              + (float)acc12[m][nf][r] * 6.103515625e-05f;
                    Yp[(size_t)ww * 128 + co] = fmaf(val, mul, bs);
                }
            }
    }
}

// ---------------------------------------------------------------------------
// PLIF layer1: Y fp32 NHWC -> spikes i8 NHWC (swizzled, conv2 input)
// ---------------------------------------------------------------------------
__global__ __launch_bounds__(256) void plif1_k(const float* __restrict__ Y,
                                               const float* __restrict__ wp,
                                               signed char* __restrict__ S) {
    int gid = blockIdx.x * 256 + threadIdx.x;     // 0..200703
    int cg = gid & 7;
    int pix = gid >> 3;                           // b*3136 + hw
    int w = (pix % HW) % 56;
    float k = 1.f / (1.f + expf(-wp[0]));
    float v[16];
#pragma unroll
    for (int e = 0; e < 16; ++e) v[e] = 0.f;
    size_t base = (size_t)pix * 128 + cg * 16;
    size_t obase = (size_t)pix * 128 + ((cg ^ (w & 7)) << 4);
#pragma unroll
    for (int t = 0; t < 4; ++t) {
        const float* yp = Y + (size_t)t * NLOC + base;
        union { signed char b[16]; int4v iv; } u;
#pragma unroll
        for (int e4 = 0; e4 < 4; ++e4) {
            float4 xv = *(const float4*)(yp + e4 * 4);
            float xe[4] = {xv.x, xv.y, xv.z, xv.w};
#pragma unroll
            for (int j = 0; j < 4; ++j) {
                int e = e4 * 4 + j;
                v[e] = v[e] + (xe[j] - v[e]) * k;
                bool sp = v[e] >= 1.f;
                u.b[e] = sp ? 1 : 0;
                v[e] = sp ? 0.f : v[e];
            }
        }
        *(int4v*)(S + (size_t)t * NLOC + obase) = u.iv;
    }
}

// ---------------------------------------------------------------------------
// PLIF layer2 + residual: Y2 fp32 NHWC + x fp32 NCHW -> out fp32 NCHW
// ---------------------------------------------------------------------------
__global__ __launch_bounds__(256) void plif2_k(const float* __restrict__ Y2,
                                               const float* __restrict__ wp,
                                               const float* __restrict__ x,
                                               float* __restrict__ out) {
    __shared__ float xs[4 * 56 * 65];
    int bid = blockIdx.x;
    int half = bid & 1;
    int bh = bid >> 1;
    int b = bh / 56, h = bh % 56;
    int tid = threadIdx.x;
    float k = 1.f / (1.f + expf(-wp[0]));
#pragma unroll
    for (int j = 0; j < 14; ++j) {
        int idx = tid + j * 256;              // 0..3583
        int t = idx / 896;
        int rem = idx - t * 896;
        int ww = rem >> 4, cq = rem & 15;
        float4 v = *(const float4*)(Y2 + ((size_t)(t * 8 + b) * HW + h * 56 + ww) * 128
                                       + half * 64 + cq * 4);
        float* dst = &xs[(t * 56 + ww) * 65 + cq * 4];
        dst[0] = v.x; dst[1] = v.y; dst[2] = v.z; dst[3] = v.w;
    }
    __syncthreads();
#pragma unroll
    for (int j = 0; j < 14; ++j) {
        int idx = tid + j * 256;              // c*56 + w
        int c = idx / 56, ww = idx - c * 56;
        float v = 0.f;
        size_t xo = ((size_t)b * 128 + half * 64 + c) * HW + h * 56 + ww;
#pragma unroll
        for (int t = 0; t < 4; ++t) {
            float yv = xs[(t * 56 + ww) * 65 + c];
            v = v + (yv - v) * k;
            bool sp = v >= 1.f;
            size_t o = xo + (size_t)t * NLOC;
            out[o] = (sp ? 1.f : 0.f) + x[o];
            v = sp ? 0.f : v;
        }
    }
}

// ---------------------------------------------------------------------------
extern "C" void kernel_launch(void* const* d_in, const int* in_sizes, int n_in,
                              void* d_out, int out_size, void* d_ws, size_t ws_size,
                              hipStream_t stream) {
    const float* x    = (const float*)d_in[0];
    const float* w1   = (const float*)d_in[1];
    const float* g1   = (const float*)d_in[2];
    const float* be1  = (const float*)d_in[3];
    const float* mu1  = (const float*)d_in[4];
    const float* va1  = (const float*)d_in[5];
    const float* tau1 = (const float*)d_in[6];
    const float* w2   = (const float*)d_in[7];
    const float* g2   = (const float*)d_in[8];
    const float* be2  = (const float*)d_in[9];
    const float* mu2  = (const float*)d_in[10];
    const float* va2  = (const float*)d_in[11];
    const float* tau2 = (const float*)d_in[12];
    float* out = (float*)d_out;

    char* ws = (char*)d_ws;
    signed char* bufA = (signed char*)ws;          // i8 [NE]: Xt then S1
    float* bufY = (float*)(ws + NE);               // fp32 [NE]: Y1 then Y2
    float* sv1  = (float*)(ws + 5 * NE);
    float* sv2  = sv1 + 128;
    signed char* Bq1 = (signed char*)(ws + 5 * NE + 1024);
    signed char* Bq2 = Bq1 + 27 * 16384;

    scale_k<<<128, 128, 0, stream>>>(w1, sv1);
    scale_k<<<128, 128, 0, stream>>>(w2, sv2);
    repack_k<<<36, 256, 0, stream>>>(w1, sv1, Bq1);
    repack_k<<<36, 256, 0, stream>>>(w2, sv2, Bq2);
    xpose_k<<<NIMG * 56, 256, 0, stream>>>(x, bufA);

    conv_mfma_k<<<NIMG * 56, 256, 0, stream>>>(bufA, Bq1, sv1, g1, be1, mu1, va1, bufY);
    plif1_k<<<784, 256, 0, stream>>>(bufY, tau1, bufA);
    conv_mfma_k<<<NIMG * 56, 256, 0, stream>>>(bufA, Bq2, sv2, g2, be2, mu2, va2, bufY);
    plif2_k<<<B_ * 56 * 2, 256, 0, stream>>>(bufY, tau2, x, out);
}

// Round 6
// 207.789 us; speedup vs baseline: 2.5778x; 2.5778x over previous
//
#include <hip/hip_runtime.h>
#include <math.h>

// Dims fixed: T=4, B=8, C=128, H=W=56, mid=128.
#define T_ 4
#define B_ 8
#define C_ 128
#define H_ 56
#define W_ 56
#define NIMG (T_ * B_)              // 32
#define HW (H_ * W_)                // 3136
#define NLOC ((size_t)B_ * C_ * HW) // 3211264 per-t elements
#define NE ((size_t)T_ * NLOC)      // 12845056

typedef __attribute__((ext_vector_type(4))) int   int4v;
typedef __attribute__((ext_vector_type(4))) float float4v;

#define GLOAD_LDS16(gp, lp) \
    __builtin_amdgcn_global_load_lds((const __attribute__((address_space(1))) unsigned int*)(gp), \
                                     (__attribute__((address_space(3))) unsigned int*)(lp), 16, 0, 0)

// ---------------------------------------------------------------------------
// per-co scale: sv[co] = max_{ci,tap}|w[co][ci][tap]| / 127
// ---------------------------------------------------------------------------
__global__ __launch_bounds__(128) void scale_k(const float* __restrict__ w,
                                               float* __restrict__ sv) {
    __shared__ float red[128];
    int co = blockIdx.x, t = threadIdx.x;
    const float* p = w + (size_t)co * 1152 + t * 9;
    float m = 0.f;
#pragma unroll
    for (int j = 0; j < 9; ++j) m = fmaxf(m, fabsf(p[j]));
    red[t] = m; __syncthreads();
    for (int off = 64; off; off >>= 1) {
        if (t < off) red[t] = fmaxf(red[t], red[t + off]);
        __syncthreads();
    }
    if (t == 0) sv[co] = fmaxf(red[0], 1e-20f) / 127.f;
}

// ---------------------------------------------------------------------------
// repack weights -> 27 i8 tiles of 16KB (stage = tap*3 + split), LDS-DMA layout:
// tile byte L(co,ci) = co*128 + ((ci>>4 ^ (co&7))<<4) + (ci&15)
// 3-way split: w = s*(q1 + q2/128 + q3/16384), exact-int accumulation.
// ---------------------------------------------------------------------------
__global__ __launch_bounds__(256) void repack_k(const float* __restrict__ w,
                                                const float* __restrict__ sv,
                                                signed char* __restrict__ Bs) {
    int idx = blockIdx.x * 256 + threadIdx.x;
    if (idx >= 9 * 1024) return;
    int tap = idx >> 10;
    int rem = idx & 1023;
    int co = rem >> 3, cig = rem & 7;
    double s = (double)sv[co];
    union { signed char b[16]; int4v v; } q[3];
#pragma unroll
    for (int e = 0; e < 16; ++e) {
        int ci = cig * 16 + e;
        double v = (double)w[((size_t)co * 128 + ci) * 9 + tap];
        double q1 = rint(v / s);
        double r1 = v - s * q1;
        double q2 = rint(r1 * 128.0 / s);
        double r2 = r1 - s * q2 * 0.0078125;
        double q3 = rint(r2 * 16384.0 / s);
        q[0].b[e] = (signed char)(int)q1;
        q[1].b[e] = (signed char)(int)q2;
        q[2].b[e] = (signed char)(int)q3;
    }
    int Lb = co * 128 + ((cig ^ (co & 7)) << 4);
#pragma unroll
    for (int sp = 0; sp < 3; ++sp)
        *(int4v*)(Bs + (size_t)(tap * 3 + sp) * 16384 + Lb) = q[sp].v;
}

// ---------------------------------------------------------------------------
// x fp32 NCHW -> Xt i8 NHWC, ci-slot XOR-swizzled by (w&7):
// byte at px*128 + slot*16 + b holds ci = (slot ^ (px&7))*16 + b
// ---------------------------------------------------------------------------
__global__ __launch_bounds__(256) void xpose_k(const float* __restrict__ x,
                                               signed char* __restrict__ Xt) {
    __shared__ float xs[128][57];
    int n = blockIdx.x / 56, h = blockIdx.x % 56;
    int tid = threadIdx.x;
    const float* xp = x + (size_t)n * 128 * HW + h * 56;
#pragma unroll
    for (int j = 0; j < 7; ++j) {
        int idx = tid + j * 256;              // 0..1791 = c*14 + wq
        int c = idx / 14, wq = idx - c * 14;
        float4 v = *(const float4*)(xp + (size_t)c * HW + wq * 4);
        xs[c][wq * 4 + 0] = v.x; xs[c][wq * 4 + 1] = v.y;
        xs[c][wq * 4 + 2] = v.z; xs[c][wq * 4 + 3] = v.w;
    }
    __syncthreads();
    signed char* Op = Xt + ((size_t)n * HW + h * 56) * 128;
#pragma unroll
    for (int j = 0; j < 2; ++j) {
        int idx = tid + j * 256;              // 0..447 = ww*8 + slot
        if (idx < 448) {
            int ww = idx >> 3, sl = idx & 7;
            int cg = sl ^ (ww & 7);
            union { signed char b[16]; int4v v; } u;
#pragma unroll
            for (int e = 0; e < 16; ++e)
                u.b[e] = (xs[cg * 16 + e][ww] >= 0.5f) ? 1 : 0;
            *(int4v*)(Op + ww * 128 + sl * 16) = u.v;
        }
    }
}

// ---------------------------------------------------------------------------
// conv3x3 SAME + BN, i8 MFMA implicit GEMM.
// Block: 512 thr / 8 waves = 2 rows x 4 co-quarters. Wave: 64px x 32co.
// A: 4 rows staged once in LDS (32KB, swizzled). B: 27 x 16KB tiles,
// double-buffered via global_load_lds, counted vmcnt(2).
// THREE exact-int accumulator chains (one per split) -> zero in-loop VALU;
// single epilogue fold. Stage loop fully unrolled for static acc indexing.
// ---------------------------------------------------------------------------
__global__ __launch_bounds__(512, 2) void conv_mfma_k(
        const signed char* __restrict__ Xt,   // i8 NHWC swizzled [32][3136][128]
        const signed char* __restrict__ Bs,   // 27 x 16KB tiles
        const float* __restrict__ sv,
        const float* __restrict__ gamma, const float* __restrict__ beta,
        const float* __restrict__ mean,  const float* __restrict__ var,
        float* __restrict__ Y) {              // fp32 NHWC
    __shared__ signed char aA[4 * 8192];      // rows h0-1..h0+2 x 64px x 128ci
    __shared__ signed char bB[2][16384];

    const int tid = threadIdx.x;
    const int lane = tid & 63;
    const int wave = tid >> 6;
    const int fr = lane & 15, fq = lane >> 4;
    const int row_local = wave >> 2;          // 0..1
    const int q = wave & 3;                   // co-quarter
    const int img = blockIdx.x / 28;
    const int h0 = (blockIdx.x % 28) * 2;
    const int h = h0 + row_local;

#define STAGEB(sidx, buf) do {                                                    \
        const char* _src = (const char*)Bs + (size_t)(sidx) * 16384 + tid * 16;   \
        char* _dst = (char*)&bB[(buf)][0] + tid * 16;                             \
        GLOAD_LDS16(_src, _dst);                                                  \
        GLOAD_LDS16(_src + 8192, _dst + 8192);                                    \
    } while (0)

#define LOADA(tap) do {                                                           \
        int _dh = (tap) / 3, _dw = (tap) % 3;                                     \
        int _hh = h + _dh - 1;                                                    \
        bool _hok = (unsigned)_hh < 56u;                                          \
        int _r4 = row_local + _dh;                                                \
        _Pragma("unroll")                                                         \
        for (int _m = 0; _m < 4; ++_m) {                                          \
            int _px = _m * 16 + fr + _dw - 1;                                     \
            bool _ok = _hok && ((unsigned)_px < 56u);                             \
            int _pxc = _ok ? _px : 0;                                             \
            const signed char* _base = aA + _r4 * 8192 + _pxc * 128;              \
            _Pragma("unroll")                                                     \
            for (int _ks = 0; _ks < 2; ++_ks) {                                   \
                int _sl = (_ks * 4 + fq) ^ (_pxc & 7);                            \
                int4v _v = *(const int4v*)(_base + _sl * 16);                     \
                a[_m][_ks] = _ok ? _v : zi;                                       \
            }                                                                     \
        }                                                                         \
    } while (0)

    // ---- prologue: stage A (4 rows) + B tile 0 ----
    {
        const signed char* XtN = Xt + (size_t)img * HW * 128;
#pragma unroll
        for (int i = 0; i < 4; ++i) {
            int hh = h0 - 1 + i;
            hh = hh < 0 ? 0 : (hh > 55 ? 55 : hh);    // clamp (masked at use)
            const char* src = (const char*)(XtN + (size_t)hh * 7168);
            GLOAD_LDS16(src + tid * 16, (char*)aA + i * 8192 + tid * 16);
        }
        STAGEB(0, 0);
        asm volatile("s_waitcnt vmcnt(0)" ::: "memory");
        __builtin_amdgcn_sched_barrier(0);
        __builtin_amdgcn_s_barrier();
    }

    const int4v zi = (int4v){0, 0, 0, 0};
    int4v acc[3][4][2];
#pragma unroll
    for (int sp = 0; sp < 3; ++sp)
#pragma unroll
        for (int m = 0; m < 4; ++m) {
            acc[sp][m][0] = zi; acc[sp][m][1] = zi;
        }
    int4v a[4][2];
    LOADA(0);

    // ---- K-loop: 9 taps x 3 splits, dbuf B, counted vmcnt ----
#pragma unroll
    for (int tap = 0; tap < 9; ++tap) {
#pragma unroll
        for (int sp = 0; sp < 3; ++sp) {
            const int s = tap * 3 + sp;
            if (s < 26) {
                STAGEB(s + 1, (s & 1) ^ 1);
                asm volatile("s_waitcnt vmcnt(2)" ::: "memory");  // s done; s+1 in flight
            } else {
                asm volatile("s_waitcnt vmcnt(0)" ::: "memory");
            }
            __builtin_amdgcn_sched_barrier(0);
            __builtin_amdgcn_s_barrier();

            const signed char* bp = &bB[s & 1][0];
            const int cob = (q * 32 + fr) * 128;
            const int sl0 = (fq ^ (fr & 7)) << 4;
            const int sl1 = ((4 + fq) ^ (fr & 7)) << 4;
            int4v b00 = *(const int4v*)(bp + cob + sl0);
            int4v b10 = *(const int4v*)(bp + cob + sl1);
            int4v b01 = *(const int4v*)(bp + cob + 2048 + sl0);
            int4v b11 = *(const int4v*)(bp + cob + 2048 + sl1);

            __builtin_amdgcn_s_setprio(1);
#pragma unroll
            for (int m = 0; m < 4; ++m) {
                acc[sp][m][0] = __builtin_amdgcn_mfma_i32_16x16x64_i8(a[m][0], b00, acc[sp][m][0], 0, 0, 0);
                acc[sp][m][0] = __builtin_amdgcn_mfma_i32_16x16x64_i8(a[m][1], b10, acc[sp][m][0], 0, 0, 0);
                acc[sp][m][1] = __builtin_amdgcn_mfma_i32_16x16x64_i8(a[m][0], b01, acc[sp][m][1], 0, 0, 0);
                acc[sp][m][1] = __builtin_amdgcn_mfma_i32_16x16x64_i8(a[m][1], b11, acc[sp][m][1], 0, 0, 0);
            }
            __builtin_amdgcn_s_setprio(0);

            if (sp == 2 && tap < 8) LOADA(tap + 1);   // a[] consumed; prefetch next tap
            asm volatile("s_waitcnt lgkmcnt(0)" ::: "memory");
            __builtin_amdgcn_sched_barrier(0);
            __builtin_amdgcn_s_barrier();             // buf[s&1] safe to overwrite
        }
    }

    // ---- epilogue: fold splits + BN + store, Y NHWC fp32 ----
    float* Yp = Y + ((size_t)img * HW + h * 56) * 128;
#pragma unroll
    for (int nf = 0; nf < 2; ++nf) {
        int co = q * 32 + nf * 16 + fr;
        float s = sv[co];
        float iv = gamma[co] / sqrtf(var[co] + 1e-5f);
        float mul = s * iv;
        float bs = beta[co] - mean[co] * iv;
#pragma unroll
        for (int m = 0; m < 4; ++m)
#pragma unroll
            for (int r = 0; r < 4; ++r) {
                int ww = m * 16 + fq * 4 + r;
                if (ww < 56) {
                    float val = (float)acc[0][m][nf][r]
                              + (float)acc[1][m][nf][r] * 0.0078125f
                              + (float)acc[2][m][nf][r] * 6.103515625e-05f;
                    Yp[(size_t)ww * 128 + co] = fmaf(val, mul, bs);
                }
            }
    }
#undef STAGEB
#undef LOADA
}

// ---------------------------------------------------------------------------
// PLIF layer1: Y fp32 NHWC -> spikes i8 NHWC (swizzled, conv2 input)
// ---------------------------------------------------------------------------
__global__ __launch_bounds__(256) void plif1_k(const float* __restrict__ Y,
                                               const float* __restrict__ wp,
                                               signed char* __restrict__ S) {
    int gid = blockIdx.x * 256 + threadIdx.x;     // 0..200703
    int cg = gid & 7;
    int pix = gid >> 3;                           // b*3136 + hw
    int w = (pix % HW) % 56;
    float k = 1.f / (1.f + expf(-wp[0]));
    float v[16];
#pragma unroll
    for (int e = 0; e < 16; ++e) v[e] = 0.f;
    size_t base = (size_t)pix * 128 + cg * 16;
    size_t obase = (size_t)pix * 128 + ((cg ^ (w & 7)) << 4);
#pragma unroll
    for (int t = 0; t < 4; ++t) {
        const float* yp = Y + (size_t)t * NLOC + base;
        union { signed char b[16]; int4v iv; } u;
#pragma unroll
        for (int e4 = 0; e4 < 4; ++e4) {
            float4 xv = *(const float4*)(yp + e4 * 4);
            float xe[4] = {xv.x, xv.y, xv.z, xv.w};
#pragma unroll
            for (int j = 0; j < 4; ++j) {
                int e = e4 * 4 + j;
                v[e] = v[e] + (xe[j] - v[e]) * k;
                bool sp = v[e] >= 1.f;
                u.b[e] = sp ? 1 : 0;
                v[e] = sp ? 0.f : v[e];
            }
        }
        *(int4v*)(S + (size_t)t * NLOC + obase) = u.iv;
    }
}

// ---------------------------------------------------------------------------
// PLIF layer2 + residual: Y2 fp32 NHWC + x fp32 NCHW -> out fp32 NCHW
// ---------------------------------------------------------------------------
__global__ __launch_bounds__(256) void plif2_k(const float* __restrict__ Y2,
                                               const float* __restrict__ wp,
                                               const float* __restrict__ x,
                                               float* __restrict__ out) {
    __shared__ float xs[4 * 56 * 65];
    int bid = blockIdx.x;
    int half = bid & 1;
    int bh = bid >> 1;
    int b = bh / 56, h = bh % 56;
    int tid = threadIdx.x;
    float k = 1.f / (1.f + expf(-wp[0]));
#pragma unroll
    for (int j = 0; j < 14; ++j) {
        int idx = tid + j * 256;              // 0..3583
        int t = idx / 896;
        int rem = idx - t * 896;
        int ww = rem >> 4, cq = rem & 15;
        float4 v = *(const float4*)(Y2 + ((size_t)(t * 8 + b) * HW + h * 56 + ww) * 128
                                       + half * 64 + cq * 4);
        float* dst = &xs[(t * 56 + ww) * 65 + cq * 4];
        dst[0] = v.x; dst[1] = v.y; dst[2] = v.z; dst[3] = v.w;
    }
    __syncthreads();
#pragma unroll
    for (int j = 0; j < 14; ++j) {
        int idx = tid + j * 256;              // c*56 + w
        int c = idx / 56, ww = idx - c * 56;
        float v = 0.f;
        size_t xo = ((size_t)b * 128 + half * 64 + c) * HW + h * 56 + ww;
#pragma unroll
        for (int t = 0; t < 4; ++t) {
            float yv = xs[(t * 56 + ww) * 65 + c];
            v = v + (yv - v) * k;
            bool sp = v >= 1.f;
            size_t o = xo + (size_t)t * NLOC;
            out[o] = (sp ? 1.f : 0.f) + x[o];
            v = sp ? 0.f : v;
        }
    }
}

// ---------------------------------------------------------------------------
extern "C" void kernel_launch(void* const* d_in, const int* in_sizes, int n_in,
                              void* d_out, int out_size, void* d_ws, size_t ws_size,
                              hipStream_t stream) {
    const float* x    = (const float*)d_in[0];
    const float* w1   = (const float*)d_in[1];
    const float* g1   = (const float*)d_in[2];
    const float* be1  = (const float*)d_in[3];
    const float* mu1  = (const float*)d_in[4];
    const float* va1  = (const float*)d_in[5];
    const float* tau1 = (const float*)d_in[6];
    const float* w2   = (const float*)d_in[7];
    const float* g2   = (const float*)d_in[8];
    const float* be2  = (const float*)d_in[9];
    const float* mu2  = (const float*)d_in[10];
    const float* va2  = (const float*)d_in[11];
    const float* tau2 = (const float*)d_in[12];
    float* out = (float*)d_out;

    char* ws = (char*)d_ws;
    signed char* bufA = (signed char*)ws;          // i8 [NE]: Xt then S1
    float* bufY = (float*)(ws + NE);               // fp32 [NE]: Y1 then Y2
    float* sv1  = (float*)(ws + 5 * NE);
    float* sv2  = sv1 + 128;
    signed char* Bs1 = (signed char*)(ws + 5 * NE + 1024);
    signed char* Bs2 = Bs1 + 27 * 16384;

    scale_k<<<128, 128, 0, stream>>>(w1, sv1);
    scale_k<<<128, 128, 0, stream>>>(w2, sv2);
    repack_k<<<36, 256, 0, stream>>>(w1, sv1, Bs1);
    repack_k<<<36, 256, 0, stream>>>(w2, sv2, Bs2);
    xpose_k<<<NIMG * 56, 256, 0, stream>>>(x, bufA);

    conv_mfma_k<<<NIMG * 28, 512, 0, stream>>>(bufA, Bs1, sv1, g1, be1, mu1, va1, bufY);
    plif1_k<<<784, 256, 0, stream>>>(bufY, tau1, bufA);
    conv_mfma_k<<<NIMG * 28, 512, 0, stream>>>(bufA, Bs2, sv2, g2, be2, mu2, va2, bufY);
    plif2_k<<<B_ * 56 * 2, 256, 0, stream>>>(bufY, tau2, x, out);
}

// Round 7
// 197.806 us; speedup vs baseline: 2.7079x; 1.0505x over previous
//
#include <hip/hip_runtime.h>
#include <math.h>

// Dims fixed: T=4, B=8, C=128, H=W=56, mid=128.
#define T_ 4
#define B_ 8
#define C_ 128
#define H_ 56
#define W_ 56
#define NIMG (T_ * B_)              // 32
#define HW (H_ * W_)                // 3136
#define NLOC ((size_t)B_ * C_ * HW) // 3211264 per-t elements
#define NE ((size_t)T_ * NLOC)      // 12845056

typedef __attribute__((ext_vector_type(4))) int   int4v;
typedef __attribute__((ext_vector_type(4))) float float4v;

#define GLOAD_LDS16(gp, lp) \
    __builtin_amdgcn_global_load_lds((const __attribute__((address_space(1))) unsigned int*)(gp), \
                                     (__attribute__((address_space(3))) unsigned int*)(lp), 16, 0, 0)

// ---------------------------------------------------------------------------
// per-co scale: sv[co] = max_{ci,tap}|w[co][ci][tap]| / 127
// ---------------------------------------------------------------------------
__global__ __launch_bounds__(128) void scale_k(const float* __restrict__ w,
                                               float* __restrict__ sv) {
    __shared__ float red[128];
    int co = blockIdx.x, t = threadIdx.x;
    const float* p = w + (size_t)co * 1152 + t * 9;
    float m = 0.f;
#pragma unroll
    for (int j = 0; j < 9; ++j) m = fmaxf(m, fabsf(p[j]));
    red[t] = m; __syncthreads();
    for (int off = 64; off; off >>= 1) {
        if (t < off) red[t] = fmaxf(red[t], red[t + off]);
        __syncthreads();
    }
    if (t == 0) sv[co] = fmaxf(red[0], 1e-20f) / 127.f;
}

// ---------------------------------------------------------------------------
// repack weights -> 27 i8 tiles of 16KB (stage = tap*3 + split), LDS-DMA layout:
// tile byte L(co,ci) = co*128 + ((ci>>4 ^ (co&7))<<4) + (ci&15)
// 3-way split: w = s*(q1 + q2/128 + q3/16384), exact-int accumulation.
// ---------------------------------------------------------------------------
__global__ __launch_bounds__(256) void repack_k(const float* __restrict__ w,
                                                const float* __restrict__ sv,
                                                signed char* __restrict__ Bs) {
    int idx = blockIdx.x * 256 + threadIdx.x;
    if (idx >= 9 * 1024) return;
    int tap = idx >> 10;
    int rem = idx & 1023;
    int co = rem >> 3, cig = rem & 7;
    double s = (double)sv[co];
    union { signed char b[16]; int4v v; } q[3];
#pragma unroll
    for (int e = 0; e < 16; ++e) {
        int ci = cig * 16 + e;
        double v = (double)w[((size_t)co * 128 + ci) * 9 + tap];
        double q1 = rint(v / s);
        double r1 = v - s * q1;
        double q2 = rint(r1 * 128.0 / s);
        double r2 = r1 - s * q2 * 0.0078125;
        double q3 = rint(r2 * 16384.0 / s);
        q[0].b[e] = (signed char)(int)q1;
        q[1].b[e] = (signed char)(int)q2;
        q[2].b[e] = (signed char)(int)q3;
    }
    int Lb = co * 128 + ((cig ^ (co & 7)) << 4);
#pragma unroll
    for (int sp = 0; sp < 3; ++sp)
        *(int4v*)(Bs + (size_t)(tap * 3 + sp) * 16384 + Lb) = q[sp].v;
}

// ---------------------------------------------------------------------------
// x fp32 NCHW -> Xt i8 NHWC, ci-slot XOR-swizzled by (w&7):
// byte at px*128 + slot*16 + b holds ci = (slot ^ (px&7))*16 + b
// ---------------------------------------------------------------------------
__global__ __launch_bounds__(256) void xpose_k(const float* __restrict__ x,
                                               signed char* __restrict__ Xt) {
    __shared__ float xs[128][57];
    int n = blockIdx.x / 56, h = blockIdx.x % 56;
    int tid = threadIdx.x;
    const float* xp = x + (size_t)n * 128 * HW + h * 56;
#pragma unroll
    for (int j = 0; j < 7; ++j) {
        int idx = tid + j * 256;              // 0..1791 = c*14 + wq
        int c = idx / 14, wq = idx - c * 14;
        float4 v = *(const float4*)(xp + (size_t)c * HW + wq * 4);
        xs[c][wq * 4 + 0] = v.x; xs[c][wq * 4 + 1] = v.y;
        xs[c][wq * 4 + 2] = v.z; xs[c][wq * 4 + 3] = v.w;
    }
    __syncthreads();
    signed char* Op = Xt + ((size_t)n * HW + h * 56) * 128;
#pragma unroll
    for (int j = 0; j < 2; ++j) {
        int idx = tid + j * 256;              // 0..447 = ww*8 + slot
        if (idx < 448) {
            int ww = idx >> 3, sl = idx & 7;
            int cg = sl ^ (ww & 7);
            union { signed char b[16]; int4v v; } u;
#pragma unroll
            for (int e = 0; e < 16; ++e)
                u.b[e] = (xs[cg * 16 + e][ww] >= 0.5f) ? 1 : 0;
            *(int4v*)(Op + ww * 128 + sl * 16) = u.v;
        }
    }
}

// ---------------------------------------------------------------------------
// conv3x3 SAME + BN, i8 MFMA implicit GEMM, tap-period schedule.
// Block: 512 thr / 8 waves = 2 rows x 4 co-quarters. Wave: 64px x 32co.
// A: 4 rows staged once in LDS (32KB). B: per-tap 48KB (3 split tiles)
// single-buffered; 9 periods, 2 barriers each, 48 MFMA/wave/period.
// 80KB LDS -> 2 blocks/CU; the other block's MFMA cluster covers DMA waits.
// Tap start rotated per block (int acc chains commute exactly).
// ---------------------------------------------------------------------------
__global__ __launch_bounds__(512, 2) void conv_mfma_k(
        const signed char* __restrict__ Xt,   // i8 NHWC swizzled [32][3136][128]
        const signed char* __restrict__ Bs,   // 27 x 16KB tiles (tap*3+sp)
        const float* __restrict__ sv,
        const float* __restrict__ gamma, const float* __restrict__ beta,
        const float* __restrict__ mean,  const float* __restrict__ var,
        float* __restrict__ Y) {              // fp32 NHWC
    __shared__ signed char aA[4 * 8192];      // rows h0-1..h0+2 x 64px x 128ci
    __shared__ signed char bB[3 * 16384];     // one tap: 3 split tiles

    const int tid = threadIdx.x;
    const int lane = tid & 63;
    const int wave = tid >> 6;
    const int fr = lane & 15, fq = lane >> 4;
    const int row_local = wave >> 2;          // 0..1
    const int q = wave & 3;                   // co-quarter
    const int img = blockIdx.x / 28;
    const int h0 = (blockIdx.x % 28) * 2;
    const int h = h0 + row_local;

#define STAGE3(tp) do {                                                           \
        const char* _src = (const char*)Bs + (size_t)(tp) * 49152 + tid * 16;     \
        char* _dst = (char*)bB + tid * 16;                                        \
        _Pragma("unroll")                                                         \
        for (int _c = 0; _c < 6; ++_c)                                            \
            GLOAD_LDS16(_src + _c * 8192, _dst + _c * 8192);                      \
    } while (0)

#define LOADA(tp) do {                                                            \
        int _dh = (tp) / 3, _dw = (tp) - ((tp) / 3) * 3;                          \
        int _hh = h + _dh - 1;                                                    \
        bool _hok = (unsigned)_hh < 56u;                                          \
        int _r4 = row_local + _dh;                                                \
        _Pragma("unroll")                                                         \
        for (int _m = 0; _m < 4; ++_m) {                                          \
            int _px = _m * 16 + fr + _dw - 1;                                     \
            bool _ok = _hok && ((unsigned)_px < 56u);                             \
            int _pxc = _ok ? _px : 0;                                             \
            const signed char* _base = aA + _r4 * 8192 + _pxc * 128;              \
            _Pragma("unroll")                                                     \
            for (int _ks = 0; _ks < 2; ++_ks) {                                   \
                int _sl = (_ks * 4 + fq) ^ (_pxc & 7);                            \
                int4v _v = *(const int4v*)(_base + _sl * 16);                     \
                a[_m][_ks] = _ok ? _v : zi;                                       \
            }                                                                     \
        }                                                                         \
    } while (0)

    const int tap0 = (int)((blockIdx.x * 4u) % 9u);

    // ---- prologue: stage A (4 rows) + first tap's 3 tiles ----
    {
        const signed char* XtN = Xt + (size_t)img * HW * 128;
#pragma unroll
        for (int i = 0; i < 4; ++i) {
            int hh = h0 - 1 + i;
            hh = hh < 0 ? 0 : (hh > 55 ? 55 : hh);    // clamp (masked at use)
            const char* src = (const char*)(XtN + (size_t)hh * 7168);
            GLOAD_LDS16(src + tid * 16, (char*)aA + i * 8192 + tid * 16);
        }
        STAGE3(tap0);
        asm volatile("s_waitcnt vmcnt(0)" ::: "memory");
        __builtin_amdgcn_sched_barrier(0);
        __builtin_amdgcn_s_barrier();
    }

    const int4v zi = (int4v){0, 0, 0, 0};
    int4v acc[3][4][2];
#pragma unroll
    for (int sp = 0; sp < 3; ++sp)
#pragma unroll
        for (int m = 0; m < 4; ++m) {
            acc[sp][m][0] = zi; acc[sp][m][1] = zi;
        }
    int4v a[4][2];
    LOADA(tap0);

    const int cob = (q * 32 + fr) * 128;
    const int sl0 = (fq ^ (fr & 7)) << 4;
    const int sl1 = ((4 + fq) ^ (fr & 7)) << 4;

    // ---- 9 tap-periods ----
    for (int it = 0; it < 9; ++it) {
        int tap = tap0 + it; if (tap >= 9) tap -= 9;

        __builtin_amdgcn_s_setprio(1);
#pragma unroll
        for (int sp = 0; sp < 3; ++sp) {
            const signed char* bp = bB + sp * 16384;
            int4v b00 = *(const int4v*)(bp + cob + sl0);
            int4v b10 = *(const int4v*)(bp + cob + sl1);
            int4v b01 = *(const int4v*)(bp + cob + 2048 + sl0);
            int4v b11 = *(const int4v*)(bp + cob + 2048 + sl1);
#pragma unroll
            for (int m = 0; m < 4; ++m) {
                acc[sp][m][0] = __builtin_amdgcn_mfma_i32_16x16x64_i8(a[m][0], b00, acc[sp][m][0], 0, 0, 0);
                acc[sp][m][0] = __builtin_amdgcn_mfma_i32_16x16x64_i8(a[m][1], b10, acc[sp][m][0], 0, 0, 0);
                acc[sp][m][1] = __builtin_amdgcn_mfma_i32_16x16x64_i8(a[m][0], b01, acc[sp][m][1], 0, 0, 0);
                acc[sp][m][1] = __builtin_amdgcn_mfma_i32_16x16x64_i8(a[m][1], b11, acc[sp][m][1], 0, 0, 0);
            }
        }
        __builtin_amdgcn_s_setprio(0);
        // all waves' b-frag ds_reads retired (MFMA operands read at issue)
        __builtin_amdgcn_s_barrier();

        if (it < 8) {
            int ntap = tap + 1; if (ntap >= 9) ntap -= 9;
            STAGE3(ntap);                 // DMA into bB (all waves past reads)
            LOADA(ntap);                  // overlap ds_reads with DMA wait
            asm volatile("s_waitcnt vmcnt(0)" ::: "memory");
            __builtin_amdgcn_sched_barrier(0);
            __builtin_amdgcn_s_barrier();
        }
    }

    // ---- epilogue: fold splits + BN + store, Y NHWC fp32 ----
    float* Yp = Y + ((size_t)img * HW + h * 56) * 128;
#pragma unroll
    for (int nf = 0; nf < 2; ++nf) {
        int co = q * 32 + nf * 16 + fr;
        float s = sv[co];
        float iv = gamma[co] / sqrtf(var[co] + 1e-5f);
        float mul = s * iv;
        float bs = beta[co] - mean[co] * iv;
#pragma unroll
        for (int m = 0; m < 4; ++m)
#pragma unroll
            for (int r = 0; r < 4; ++r) {
                int ww = m * 16 + fq * 4 + r;
                if (ww < 56) {
                    float val = (float)acc[0][m][nf][r]
                              + (float)acc[1][m][nf][r] * 0.0078125f
                              + (float)acc[2][m][nf][r] * 6.103515625e-05f;
                    Yp[(size_t)ww * 128 + co] = fmaf(val, mul, bs);
                }
            }
    }
#undef STAGE3
#undef LOADA
}

// ---------------------------------------------------------------------------
// PLIF layer1: Y fp32 NHWC -> spikes i8 NHWC (swizzled, conv2 input)
// ---------------------------------------------------------------------------
__global__ __launch_bounds__(256) void plif1_k(const float* __restrict__ Y,
                                               const float* __restrict__ wp,
                                               signed char* __restrict__ S) {
    int gid = blockIdx.x * 256 + threadIdx.x;     // 0..200703
    int cg = gid & 7;
    int pix = gid >> 3;                           // b*3136 + hw
    int w = (pix % HW) % 56;
    float k = 1.f / (1.f + expf(-wp[0]));
    float v[16];
#pragma unroll
    for (int e = 0; e < 16; ++e) v[e] = 0.f;
    size_t base = (size_t)pix * 128 + cg * 16;
    size_t obase = (size_t)pix * 128 + ((cg ^ (w & 7)) << 4);
#pragma unroll
    for (int t = 0; t < 4; ++t) {
        const float* yp = Y + (size_t)t * NLOC + base;
        union { signed char b[16]; int4v iv; } u;
#pragma unroll
        for (int e4 = 0; e4 < 4; ++e4) {
            float4 xv = *(const float4*)(yp + e4 * 4);
            float xe[4] = {xv.x, xv.y, xv.z, xv.w};
#pragma unroll
            for (int j = 0; j < 4; ++j) {
                int e = e4 * 4 + j;
                v[e] = v[e] + (xe[j] - v[e]) * k;
                bool sp = v[e] >= 1.f;
                u.b[e] = sp ? 1 : 0;
                v[e] = sp ? 0.f : v[e];
            }
        }
        *(int4v*)(S + (size_t)t * NLOC + obase) = u.iv;
    }
}

// ---------------------------------------------------------------------------
// PLIF layer2 + residual: Y2 fp32 NHWC + x fp32 NCHW -> out fp32 NCHW
// ---------------------------------------------------------------------------
__global__ __launch_bounds__(256) void plif2_k(const float* __restrict__ Y2,
                                               const float* __restrict__ wp,
                                               const float* __restrict__ x,
                                               float* __restrict__ out) {
    __shared__ float xs[4 * 56 * 65];
    int bid = blockIdx.x;
    int half = bid & 1;
    int bh = bid >> 1;
    int b = bh / 56, h = bh % 56;
    int tid = threadIdx.x;
    float k = 1.f / (1.f + expf(-wp[0]));
#pragma unroll
    for (int j = 0; j < 14; ++j) {
        int idx = tid + j * 256;              // 0..3583
        int t = idx / 896;
        int rem = idx - t * 896;
        int ww = rem >> 4, cq = rem & 15;
        float4 v = *(const float4*)(Y2 + ((size_t)(t * 8 + b) * HW + h * 56 + ww) * 128
                                       + half * 64 + cq * 4);
        float* dst = &xs[(t * 56 + ww) * 65 + cq * 4];
        dst[0] = v.x; dst[1] = v.y; dst[2] = v.z; dst[3] = v.w;
    }
    __syncthreads();
#pragma unroll
    for (int j = 0; j < 14; ++j) {
        int idx = tid + j * 256;              // c*56 + w
        int c = idx / 56, ww = idx - c * 56;
        float v = 0.f;
        size_t xo = ((size_t)b * 128 + half * 64 + c) * HW + h * 56 + ww;
#pragma unroll
        for (int t = 0; t < 4; ++t) {
            float yv = xs[(t * 56 + ww) * 65 + c];
            v = v + (yv - v) * k;
            bool sp = v >= 1.f;
            size_t o = xo + (size_t)t * NLOC;
            out[o] = (sp ? 1.f : 0.f) + x[o];
            v = sp ? 0.f : v;
        }
    }
}

// ---------------------------------------------------------------------------
extern "C" void kernel_launch(void* const* d_in, const int* in_sizes, int n_in,
                              void* d_out, int out_size, void* d_ws, size_t ws_size,
                              hipStream_t stream) {
    const float* x    = (const float*)d_in[0];
    const float* w1   = (const float*)d_in[1];
    const float* g1   = (const float*)d_in[2];
    const float* be1  = (const float*)d_in[3];
    const float* mu1  = (const float*)d_in[4];
    const float* va1  = (const float*)d_in[5];
    const float* tau1 = (const float*)d_in[6];
    const float* w2   = (const float*)d_in[7];
    const float* g2   = (const float*)d_in[8];
    const float* be2  = (const float*)d_in[9];
    const float* mu2  = (const float*)d_in[10];
    const float* va2  = (const float*)d_in[11];
    const float* tau2 = (const float*)d_in[12];
    float* out = (float*)d_out;

    char* ws = (char*)d_ws;
    signed char* bufA = (signed char*)ws;          // i8 [NE]: Xt then S1
    float* bufY = (float*)(ws + NE);               // fp32 [NE]: Y1 then Y2
    float* sv1  = (float*)(ws + 5 * NE);
    float* sv2  = sv1 + 128;
    signed char* Bs1 = (signed char*)(ws + 5 * NE + 1024);
    signed char* Bs2 = Bs1 + 27 * 16384;

    scale_k<<<128, 128, 0, stream>>>(w1, sv1);
    scale_k<<<128, 128, 0, stream>>>(w2, sv2);
    repack_k<<<36, 256, 0, stream>>>(w1, sv1, Bs1);
    repack_k<<<36, 256, 0, stream>>>(w2, sv2, Bs2);
    xpose_k<<<NIMG * 56, 256, 0, stream>>>(x, bufA);

    conv_mfma_k<<<NIMG * 28, 512, 0, stream>>>(bufA, Bs1, sv1, g1, be1, mu1, va1, bufY);
    plif1_k<<<784, 256, 0, stream>>>(bufY, tau1, bufA);
    conv_mfma_k<<<NIMG * 28, 512, 0, stream>>>(bufA, Bs2, sv2, g2, be2, mu2, va2, bufY);
    plif2_k<<<B_ * 56 * 2, 256, 0, stream>>>(bufY, tau2, x, out);
}

// Round 8
// 170.197 us; speedup vs baseline: 3.1472x; 1.1622x over previous
//
#include <hip/hip_runtime.h>
#include <math.h>

// Dims fixed: T=4, B=8, C=128, H=W=56, mid=128.
#define T_ 4
#define B_ 8
#define C_ 128
#define H_ 56
#define W_ 56
#define NIMG (T_ * B_)              // 32
#define HW (H_ * W_)                // 3136
#define NLOC ((size_t)B_ * C_ * HW) // 3211264 per-t elements
#define NE ((size_t)T_ * NLOC)      // 12845056

typedef __attribute__((ext_vector_type(4))) int   int4v;

#define GLOAD_LDS16(gp, lp) \
    __builtin_amdgcn_global_load_lds((const __attribute__((address_space(1))) unsigned int*)(gp), \
                                     (__attribute__((address_space(3))) unsigned int*)(lp), 16, 0, 0)

// ---------------------------------------------------------------------------
// per-co scale: sv[co] = max_{ci,tap}|w[co][ci][tap]| / 127
// ---------------------------------------------------------------------------
__global__ __launch_bounds__(128) void scale_k(const float* __restrict__ w,
                                               float* __restrict__ sv) {
    __shared__ float red[128];
    int co = blockIdx.x, t = threadIdx.x;
    const float* p = w + (size_t)co * 1152 + t * 9;
    float m = 0.f;
#pragma unroll
    for (int j = 0; j < 9; ++j) m = fmaxf(m, fabsf(p[j]));
    red[t] = m; __syncthreads();
    for (int off = 64; off; off >>= 1) {
        if (t < off) red[t] = fmaxf(red[t], red[t + off]);
        __syncthreads();
    }
    if (t == 0) sv[co] = fmaxf(red[0], 1e-20f) / 127.f;
}

// ---------------------------------------------------------------------------
// repack weights -> 27 i8 tiles of 16KB (stage = tap*3 + split), LDS-DMA layout:
// tile byte L(co,ci) = co*128 + ((ci>>4 ^ (co&7))<<4) + (ci&15)
// 3-way split: w = s*(q1 + q2/128 + q3/16384), exact-int accumulation.
// ---------------------------------------------------------------------------
__global__ __launch_bounds__(256) void repack_k(const float* __restrict__ w,
                                                const float* __restrict__ sv,
                                                signed char* __restrict__ Bs) {
    int idx = blockIdx.x * 256 + threadIdx.x;
    if (idx >= 9 * 1024) return;
    int tap = idx >> 10;
    int rem = idx & 1023;
    int co = rem >> 3, cig = rem & 7;
    double s = (double)sv[co];
    union { signed char b[16]; int4v v; } q[3];
#pragma unroll
    for (int e = 0; e < 16; ++e) {
        int ci = cig * 16 + e;
        double v = (double)w[((size_t)co * 128 + ci) * 9 + tap];
        double q1 = rint(v / s);
        double r1 = v - s * q1;
        double q2 = rint(r1 * 128.0 / s);
        double r2 = r1 - s * q2 * 0.0078125;
        double q3 = rint(r2 * 16384.0 / s);
        q[0].b[e] = (signed char)(int)q1;
        q[1].b[e] = (signed char)(int)q2;
        q[2].b[e] = (signed char)(int)q3;
    }
    int Lb = co * 128 + ((cig ^ (co & 7)) << 4);
#pragma unroll
    for (int sp = 0; sp < 3; ++sp)
        *(int4v*)(Bs + (size_t)(tap * 3 + sp) * 16384 + Lb) = q[sp].v;
}

// ---------------------------------------------------------------------------
// x fp32 NCHW -> Xt i8 NHWC, ci-slot XOR-swizzled by (w&7):
// byte at px*128 + slot*16 + b holds ci = (slot ^ (px&7))*16 + b
// ---------------------------------------------------------------------------
__global__ __launch_bounds__(256) void xpose_k(const float* __restrict__ x,
                                               signed char* __restrict__ Xt) {
    __shared__ float xs[128][57];
    int n = blockIdx.x / 56, h = blockIdx.x % 56;
    int tid = threadIdx.x;
    const float* xp = x + (size_t)n * 128 * HW + h * 56;
#pragma unroll
    for (int j = 0; j < 7; ++j) {
        int idx = tid + j * 256;              // 0..1791 = c*14 + wq
        int c = idx / 14, wq = idx - c * 14;
        float4 v = *(const float4*)(xp + (size_t)c * HW + wq * 4);
        xs[c][wq * 4 + 0] = v.x; xs[c][wq * 4 + 1] = v.y;
        xs[c][wq * 4 + 2] = v.z; xs[c][wq * 4 + 3] = v.w;
    }
    __syncthreads();
    signed char* Op = Xt + ((size_t)n * HW + h * 56) * 128;
#pragma unroll
    for (int j = 0; j < 2; ++j) {
        int idx = tid + j * 256;              // 0..447 = ww*8 + slot
        if (idx < 448) {
            int ww = idx >> 3, sl = idx & 7;
            int cg = sl ^ (ww & 7);
            union { signed char b[16]; int4v v; } u;
#pragma unroll
            for (int e = 0; e < 16; ++e)
                u.b[e] = (xs[cg * 16 + e][ww] >= 0.5f) ? 1 : 0;
            *(int4v*)(Op + ww * 128 + sl * 16) = u.v;
        }
    }
}

// ---------------------------------------------------------------------------
// Fused conv3x3 SAME + BN + PLIF (+residual), i8 MFMA implicit GEMM.
// Block = (b, row-pair): 512 thr / 8 waves = 2 rows x 4 co-quarters; loops
// t = 0..3 internally (36 periods, tap ring continuous; A restaged per t).
// B double-buffered (2x48KB) via global_load_lds + uniform counted vmcnt(6);
// A single 32KB buffer; spike repack scratch 16KB. LDS = 144KB, 1 block/CU.
// MODE 0: out = spikes i8 NHWC swizzled.  MODE 1: out = spike + x, fp32 NCHW.
// ---------------------------------------------------------------------------
template<int MODE>
__global__ __launch_bounds__(512) void convplif_k(
        const signed char* __restrict__ Xin,  // i8 NHWC swizzled [32][3136][128]
        const signed char* __restrict__ Bs,   // 27 x 16KB tiles (tap*3+sp)
        const float* __restrict__ sv,
        const float* __restrict__ gamma, const float* __restrict__ beta,
        const float* __restrict__ mean,  const float* __restrict__ var,
        const float* __restrict__ tau,
        const float* __restrict__ xres,       // MODE1: residual input x
        void* __restrict__ outp) {
    __shared__ signed char aA[4 * 8192];      // rows h0-1..h0+2 x 64px x 128ci
    __shared__ signed char bB[2][49152];      // tap dbuf: 3 split tiles each
    __shared__ signed char sS[2 * 8192];      // spike repack scratch (MODE0)

    const int tid = threadIdx.x;
    const int lane = tid & 63;
    const int wave = tid >> 6;
    const int fr = lane & 15, fq = lane >> 4;
    const int row_local = wave >> 2;          // 0..1
    const int q = wave & 3;                   // co-quarter
    const int bb = blockIdx.x / 28;           // batch index
    const int h0 = (blockIdx.x % 28) * 2;
    const int h = h0 + row_local;
    const int tap0 = (int)((blockIdx.x * 4u) % 9u);

    const float kk = 1.f / (1.f + expf(-tau[0]));
    float mulv[2], bsv[2];
#pragma unroll
    for (int nf = 0; nf < 2; ++nf) {
        int co = q * 32 + nf * 16 + fr;
        float iv = gamma[co] / sqrtf(var[co] + 1e-5f);
        mulv[nf] = sv[co] * iv;
        bsv[nf] = beta[co] - mean[co] * iv;
    }

#define STAGEA(tt) do {                                                           \
        const signed char* _XtN = Xin + (size_t)((tt) * 8 + bb) * (HW * 128);     \
        _Pragma("unroll")                                                         \
        for (int _i = 0; _i < 4; ++_i) {                                          \
            int _hh = h0 - 1 + _i;                                                \
            _hh = _hh < 0 ? 0 : (_hh > 55 ? 55 : _hh);                            \
            GLOAD_LDS16((const char*)(_XtN + (size_t)_hh * 7168) + tid * 16,      \
                        (char*)aA + _i * 8192 + tid * 16);                        \
        }                                                                         \
    } while (0)

#define STAGEB(tp, buf) do {                                                      \
        const char* _src = (const char*)Bs + (size_t)(tp) * 49152 + tid * 16;     \
        char* _dst = (char*)&bB[(buf)][0] + tid * 16;                             \
        _Pragma("unroll")                                                         \
        for (int _c = 0; _c < 6; ++_c)                                            \
            GLOAD_LDS16(_src + _c * 8192, _dst + _c * 8192);                      \
    } while (0)

#define LOADA(tp) do {                                                            \
        int _dh = (tp) / 3, _dw = (tp) - ((tp) / 3) * 3;                          \
        int _hh = h + _dh - 1;                                                    \
        bool _hok = (unsigned)_hh < 56u;                                          \
        int _r4 = row_local + _dh;                                                \
        _Pragma("unroll")                                                         \
        for (int _m = 0; _m < 4; ++_m) {                                          \
            int _px = _m * 16 + fr + _dw - 1;                                     \
            bool _ok = _hok && ((unsigned)_px < 56u);                             \
            int _pxc = _ok ? _px : 0;                                             \
            const signed char* _base = aA + _r4 * 8192 + _pxc * 128;              \
            _Pragma("unroll")                                                     \
            for (int _ks = 0; _ks < 2; ++_ks) {                                   \
                int _sl = (_ks * 4 + fq) ^ (_pxc & 7);                            \
                int4v _v = *(const int4v*)(_base + _sl * 16);                     \
                a[_m][_ks] = _ok ? _v : zi;                                       \
            }                                                                     \
        }                                                                         \
    } while (0)

    // ---- prologue: A(t=0) + B(tap0) -> buf0, full drain once ----
    STAGEA(0);
    STAGEB(tap0, 0);
    asm volatile("s_waitcnt vmcnt(0)" ::: "memory");
    __builtin_amdgcn_sched_barrier(0);
    __builtin_amdgcn_s_barrier();

    const int4v zi = (int4v){0, 0, 0, 0};
    int4v acc[3][4][2];
#pragma unroll
    for (int sp = 0; sp < 3; ++sp)
#pragma unroll
        for (int m = 0; m < 4; ++m) { acc[sp][m][0] = zi; acc[sp][m][1] = zi; }
    float v[2][4][4];
#pragma unroll
    for (int nf = 0; nf < 2; ++nf)
#pragma unroll
        for (int m = 0; m < 4; ++m)
#pragma unroll
            for (int r = 0; r < 4; ++r) v[nf][m][r] = 0.f;
    int4v a[4][2];
    LOADA(tap0);

    const int cob = (q * 32 + fr) * 128;
    const int sl0 = (fq ^ (fr & 7)) << 4;
    const int sl1 = ((4 + fq) ^ (fr & 7)) << 4;

    // ---- 36 periods: tap ring over 4 t's, B dbuf, counted vmcnt ----
    int tap = tap0, it = 0, t = 0;
    for (int g = 0; g < 36; ++g) {
        const int ntap = (tap + 1 == 9) ? 0 : tap + 1;
        const bool tend = (it == 8);
        if (tend && t < 3) STAGEA(t + 1);       // A ordered BEFORE B-issue
        if (g < 35) {
            STAGEB(ntap, (g + 1) & 1);
            asm volatile("s_waitcnt vmcnt(6)" ::: "memory");  // retire prev B (+A)
        } else {
            asm volatile("s_waitcnt vmcnt(0)" ::: "memory");
        }
        __builtin_amdgcn_sched_barrier(0);
        __builtin_amdgcn_s_barrier();

        const signed char* bbase = &bB[g & 1][0];
        __builtin_amdgcn_s_setprio(1);
#pragma unroll
        for (int sp = 0; sp < 3; ++sp) {
            const signed char* bp = bbase + sp * 16384;
            int4v b00 = *(const int4v*)(bp + cob + sl0);
            int4v b10 = *(const int4v*)(bp + cob + sl1);
            int4v b01 = *(const int4v*)(bp + cob + 2048 + sl0);
            int4v b11 = *(const int4v*)(bp + cob + 2048 + sl1);
#pragma unroll
            for (int m = 0; m < 4; ++m) {
                acc[sp][m][0] = __builtin_amdgcn_mfma_i32_16x16x64_i8(a[m][0], b00, acc[sp][m][0], 0, 0, 0);
                acc[sp][m][0] = __builtin_amdgcn_mfma_i32_16x16x64_i8(a[m][1], b10, acc[sp][m][0], 0, 0, 0);
                acc[sp][m][1] = __builtin_amdgcn_mfma_i32_16x16x64_i8(a[m][0], b01, acc[sp][m][1], 0, 0, 0);
                acc[sp][m][1] = __builtin_amdgcn_mfma_i32_16x16x64_i8(a[m][1], b11, acc[sp][m][1], 0, 0, 0);
            }
        }
        __builtin_amdgcn_s_setprio(0);

        if (g < 35) LOADA(ntap);                // reads A(t) or fresh A(t+1)
        asm volatile("s_waitcnt lgkmcnt(0)" ::: "memory");
        __builtin_amdgcn_sched_barrier(0);
        __builtin_amdgcn_s_barrier();           // bB[g&1] safe to overwrite @g+1

        if (tend) {
            // ---- per-t epilogue: fold + BN + PLIF (+store) ----
            if (MODE == 0) {
                signed char* S1 = (signed char*)outp;
#pragma unroll
                for (int nf = 0; nf < 2; ++nf)
#pragma unroll
                    for (int m = 0; m < 4; ++m)
#pragma unroll
                        for (int r = 0; r < 4; ++r) {
                            int px = m * 16 + fq * 4 + r;
                            float val = (float)acc[0][m][nf][r]
                                      + (float)acc[1][m][nf][r] * 0.0078125f
                                      + (float)acc[2][m][nf][r] * 6.103515625e-05f;
                            float y = fmaf(val, mulv[nf], bsv[nf]);
                            float vv = v[nf][m][r];
                            vv = vv + (y - vv) * kk;
                            bool spk = vv >= 1.f;
                            v[nf][m][r] = spk ? 0.f : vv;
                            sS[row_local * 8192 + px * 128 + q * 32 + nf * 16 + fr] = spk ? 1 : 0;
                        }
                asm volatile("s_waitcnt lgkmcnt(0)" ::: "memory");
                __builtin_amdgcn_s_barrier();
                const size_t imgb = (size_t)(t * 8 + bb) * HW;
#pragma unroll
                for (int cc = 0; cc < 2; ++cc) {
                    int chunk = tid + cc * 512;
                    int row = chunk >> 9, rem = chunk & 511;
                    int px = rem >> 3, cg = rem & 7;
                    if (px < 56) {
                        int4v v16 = *(const int4v*)(sS + row * 8192 + px * 128 + cg * 16);
                        *(int4v*)(S1 + (imgb + (size_t)(h0 + row) * 56 + px) * 128
                                     + ((cg ^ (px & 7)) << 4)) = v16;
                    }
                }
            } else {
                float* outw = (float*)outp;
#pragma unroll
                for (int nf = 0; nf < 2; ++nf) {
                    const size_t cobase = ((size_t)(t * 8 + bb) * 128 + q * 32 + nf * 16 + fr) * HW
                                        + (size_t)h * 56;
#pragma unroll
                    for (int m = 0; m < 4; ++m) {
                        int px0 = m * 16 + fq * 4;
                        float o4[4];
#pragma unroll
                        for (int r = 0; r < 4; ++r) {
                            float val = (float)acc[0][m][nf][r]
                                      + (float)acc[1][m][nf][r] * 0.0078125f
                                      + (float)acc[2][m][nf][r] * 6.103515625e-05f;
                            float y = fmaf(val, mulv[nf], bsv[nf]);
                            float vv = v[nf][m][r];
                            vv = vv + (y - vv) * kk;
                            bool spk = vv >= 1.f;
                            v[nf][m][r] = spk ? 0.f : vv;
                            o4[r] = spk ? 1.f : 0.f;
                        }
                        if (px0 < 56) {
                            float4 xv = *(const float4*)(xres + cobase + px0);
                            float4 ov = make_float4(o4[0] + xv.x, o4[1] + xv.y,
                                                    o4[2] + xv.z, o4[3] + xv.w);
                            *(float4*)(outw + cobase + px0) = ov;
                        }
                    }
                }
            }
#pragma unroll
            for (int sp = 0; sp < 3; ++sp)
#pragma unroll
                for (int m = 0; m < 4; ++m) { acc[sp][m][0] = zi; acc[sp][m][1] = zi; }
            t++; it = 0;
        } else {
            it++;
        }
        tap = ntap;
    }
#undef STAGEA
#undef STAGEB
#undef LOADA
}

// ---------------------------------------------------------------------------
extern "C" void kernel_launch(void* const* d_in, const int* in_sizes, int n_in,
                              void* d_out, int out_size, void* d_ws, size_t ws_size,
                              hipStream_t stream) {
    const float* x    = (const float*)d_in[0];
    const float* w1   = (const float*)d_in[1];
    const float* g1   = (const float*)d_in[2];
    const float* be1  = (const float*)d_in[3];
    const float* mu1  = (const float*)d_in[4];
    const float* va1  = (const float*)d_in[5];
    const float* tau1 = (const float*)d_in[6];
    const float* w2   = (const float*)d_in[7];
    const float* g2   = (const float*)d_in[8];
    const float* be2  = (const float*)d_in[9];
    const float* mu2  = (const float*)d_in[10];
    const float* va2  = (const float*)d_in[11];
    const float* tau2 = (const float*)d_in[12];
    float* out = (float*)d_out;

    char* ws = (char*)d_ws;
    signed char* Xt  = (signed char*)ws;           // i8 [NE]
    signed char* S1  = (signed char*)(ws + NE);    // i8 [NE]
    float* sv1  = (float*)(ws + 2 * NE);
    float* sv2  = sv1 + 128;
    signed char* Bs1 = (signed char*)(ws + 2 * NE + 1024);
    signed char* Bs2 = Bs1 + 27 * 16384;

    scale_k<<<128, 128, 0, stream>>>(w1, sv1);
    scale_k<<<128, 128, 0, stream>>>(w2, sv2);
    repack_k<<<36, 256, 0, stream>>>(w1, sv1, Bs1);
    repack_k<<<36, 256, 0, stream>>>(w2, sv2, Bs2);
    xpose_k<<<NIMG * 56, 256, 0, stream>>>(x, Xt);

    convplif_k<0><<<B_ * 28, 512, 0, stream>>>(Xt, Bs1, sv1, g1, be1, mu1, va1,
                                               tau1, x, (void*)S1);
    convplif_k<1><<<B_ * 28, 512, 0, stream>>>(S1, Bs2, sv2, g2, be2, mu2, va2,
                                               tau2, x, (void*)out);
}

// Round 9
// 161.032 us; speedup vs baseline: 3.3263x; 1.0569x over previous
//
#include <hip/hip_runtime.h>
#include <math.h>

// Dims fixed: T=4, B=8, C=128, H=W=56, mid=128.
#define T_ 4
#define B_ 8
#define C_ 128
#define H_ 56
#define W_ 56
#define NIMG (T_ * B_)              // 32
#define HW (H_ * W_)                // 3136
#define NLOC ((size_t)B_ * C_ * HW) // 3211264 per-t elements
#define NE ((size_t)T_ * NLOC)      // 12845056
#define APITCH 8448                 // 66 px-slots * 128B (slot0 + slots57..65 are zero pad)

typedef __attribute__((ext_vector_type(4))) int   int4v;

#define GLOAD_LDS16(gp, lp) \
    __builtin_amdgcn_global_load_lds((const __attribute__((address_space(1))) unsigned int*)(gp), \
                                     (__attribute__((address_space(3))) unsigned int*)(lp), 16, 0, 0)

// ---------------------------------------------------------------------------
// per-co scale: sv[co] = max_{ci,tap}|w[co][ci][tap]| / 127
// ---------------------------------------------------------------------------
__global__ __launch_bounds__(128) void scale_k(const float* __restrict__ w,
                                               float* __restrict__ sv) {
    __shared__ float red[128];
    int co = blockIdx.x, t = threadIdx.x;
    const float* p = w + (size_t)co * 1152 + t * 9;
    float m = 0.f;
#pragma unroll
    for (int j = 0; j < 9; ++j) m = fmaxf(m, fabsf(p[j]));
    red[t] = m; __syncthreads();
    for (int off = 64; off; off >>= 1) {
        if (t < off) red[t] = fmaxf(red[t], red[t + off]);
        __syncthreads();
    }
    if (t == 0) sv[co] = fmaxf(red[0], 1e-20f) / 127.f;
}

// ---------------------------------------------------------------------------
// repack weights -> 27 i8 tiles of 16KB (stage = tap*3 + split), LDS-DMA layout:
// tile byte L(co,ci) = co*128 + ((ci>>4 ^ (co&7))<<4) + (ci&15)
// 3-way split: w = s*(q1 + q2/128 + q3/16384), exact-int accumulation.
// ---------------------------------------------------------------------------
__global__ __launch_bounds__(256) void repack_k(const float* __restrict__ w,
                                                const float* __restrict__ sv,
                                                signed char* __restrict__ Bs) {
    int idx = blockIdx.x * 256 + threadIdx.x;
    if (idx >= 9 * 1024) return;
    int tap = idx >> 10;
    int rem = idx & 1023;
    int co = rem >> 3, cig = rem & 7;
    double s = (double)sv[co];
    union { signed char b[16]; int4v v; } q[3];
#pragma unroll
    for (int e = 0; e < 16; ++e) {
        int ci = cig * 16 + e;
        double v = (double)w[((size_t)co * 128 + ci) * 9 + tap];
        double q1 = rint(v / s);
        double r1 = v - s * q1;
        double q2 = rint(r1 * 128.0 / s);
        double r2 = r1 - s * q2 * 0.0078125;
        double q3 = rint(r2 * 16384.0 / s);
        q[0].b[e] = (signed char)(int)q1;
        q[1].b[e] = (signed char)(int)q2;
        q[2].b[e] = (signed char)(int)q3;
    }
    int Lb = co * 128 + ((cig ^ (co & 7)) << 4);
#pragma unroll
    for (int sp = 0; sp < 3; ++sp)
        *(int4v*)(Bs + (size_t)(tap * 3 + sp) * 16384 + Lb) = q[sp].v;
}

// ---------------------------------------------------------------------------
// x fp32 NCHW -> Xt i8 NHWC, ci-slot XOR-swizzled by (w&7):
// byte at px*128 + slot*16 + b holds ci = (slot ^ (px&7))*16 + b
// ---------------------------------------------------------------------------
__global__ __launch_bounds__(256) void xpose_k(const float* __restrict__ x,
                                               signed char* __restrict__ Xt) {
    __shared__ float xs[128][57];
    int n = blockIdx.x / 56, h = blockIdx.x % 56;
    int tid = threadIdx.x;
    const float* xp = x + (size_t)n * 128 * HW + h * 56;
#pragma unroll
    for (int j = 0; j < 7; ++j) {
        int idx = tid + j * 256;              // 0..1791 = c*14 + wq
        int c = idx / 14, wq = idx - c * 14;
        float4 v = *(const float4*)(xp + (size_t)c * HW + wq * 4);
        xs[c][wq * 4 + 0] = v.x; xs[c][wq * 4 + 1] = v.y;
        xs[c][wq * 4 + 2] = v.z; xs[c][wq * 4 + 3] = v.w;
    }
    __syncthreads();
    signed char* Op = Xt + ((size_t)n * HW + h * 56) * 128;
#pragma unroll
    for (int j = 0; j < 2; ++j) {
        int idx = tid + j * 256;              // 0..447 = ww*8 + slot
        if (idx < 448) {
            int ww = idx >> 3, sl = idx & 7;
            int cg = sl ^ (ww & 7);
            union { signed char b[16]; int4v v; } u;
#pragma unroll
            for (int e = 0; e < 16; ++e)
                u.b[e] = (xs[cg * 16 + e][ww] >= 0.5f) ? 1 : 0;
            *(int4v*)(Op + ww * 128 + sl * 16) = u.v;
        }
    }
}

// ---------------------------------------------------------------------------
// Fused conv3x3 SAME + BN + PLIF (+residual), i8 MFMA implicit GEMM.
// Block = (b, row-pair): 512 thr / 8 waves = 2 rows x 4 co-quarters;
// t = 0..3 internally (36 periods). B dbuf (2x48KB) + counted vmcnt;
// A zero-padded rows (no masks in LOADA); next-tap a-loads interleaved
// into the MFMA cluster; drains only at it==7 and g==35.
// MODE 0: out = spikes i8 NHWC swizzled.  MODE 1: out = spike + x, fp32 NCHW.
// ---------------------------------------------------------------------------
template<int MODE>
__global__ __launch_bounds__(512) void convplif_k(
        const signed char* __restrict__ Xin,  // i8 NHWC swizzled [32][3136][128]
        const signed char* __restrict__ Bs,   // 27 x 16KB tiles (tap*3+sp)
        const float* __restrict__ sv,
        const float* __restrict__ gamma, const float* __restrict__ beta,
        const float* __restrict__ mean,  const float* __restrict__ var,
        const float* __restrict__ tau,
        const float* __restrict__ xres,       // MODE1: residual input x
        void* __restrict__ outp) {
    __shared__ signed char aA[4 * APITCH];    // 4 row-slots, zero-padded px slots
    __shared__ signed char bB[2][49152];      // tap dbuf: 3 split tiles each
    __shared__ signed char sS[2 * 8192];      // spike repack scratch (MODE0)

    const int tid = threadIdx.x;
    const int lane = tid & 63;
    const int wave = tid >> 6;
    const int fr = lane & 15, fq = lane >> 4;
    const int row_local = wave >> 2;          // 0..1
    const int q = wave & 3;                   // co-quarter
    const int bb = blockIdx.x / 28;           // batch index
    const int h0 = (blockIdx.x % 28) * 2;
    const int h = h0 + row_local;
    const int tap0 = (int)((blockIdx.x * 4u) % 9u);
    const int nA = (h0 == 0 || h0 == 54) ? 3 : 4;   // A rows staged per t

    const float kk = 1.f / (1.f + expf(-tau[0]));
    float mulv[2], bsv[2];
#pragma unroll
    for (int nf = 0; nf < 2; ++nf) {
        int co = q * 32 + nf * 16 + fr;
        float iv = gamma[co] / sqrtf(var[co] + 1e-5f);
        mulv[nf] = sv[co] * iv;
        bsv[nf] = beta[co] - mean[co] * iv;
    }

    const int4v zi = (int4v){0, 0, 0, 0};

#define STAGEA(tt) do {                                                           \
        const signed char* _XtN = Xin + (size_t)((tt) * 8 + bb) * (HW * 128);     \
        if (tid < 448) {                                                          \
            _Pragma("unroll")                                                     \
            for (int _i = 0; _i < 4; ++_i) {                                      \
                int _hh = h0 - 1 + _i;                                            \
                if ((unsigned)_hh < 56u)                                          \
                    GLOAD_LDS16((const char*)(_XtN + (size_t)_hh * 7168) + tid * 16, \
                                (char*)aA + _i * APITCH + 128 + tid * 16);        \
            }                                                                     \
        }                                                                         \
    } while (0)

#define STAGEB(tp, buf) do {                                                      \
        const char* _src = (const char*)Bs + (size_t)(tp) * 49152 + tid * 16;     \
        char* _dst = (char*)&bB[(buf)][0] + tid * 16;                             \
        _Pragma("unroll")                                                         \
        for (int _c = 0; _c < 6; ++_c)                                            \
            GLOAD_LDS16(_src + _c * 8192, _dst + _c * 8192);                      \
    } while (0)

    // pure loads, no masks: pad slots are zero
#define LOADA(tp) do {                                                            \
        const int _dh = (tp) / 3, _dw = (tp) - ((tp) / 3) * 3;                    \
        const signed char* _rb = aA + (row_local + _dh) * APITCH;                 \
        _Pragma("unroll")                                                         \
        for (int _m = 0; _m < 4; ++_m) {                                          \
            int _px1 = _m * 16 + fr + _dw;                                        \
            int _k7 = (_px1 - 1) & 7;                                             \
            const signed char* _bp = _rb + _px1 * 128;                            \
            a[_m][0] = *(const int4v*)(_bp + ((fq ^ _k7) << 4));                  \
            a[_m][1] = *(const int4v*)(_bp + (((4 + fq) ^ _k7) << 4));            \
        }                                                                         \
    } while (0)

    // ---- prologue: zero pads, stage A(0)+B(tap0), drain once ----
    for (int j = tid; j < 320; j += 512) {
        int row = j / 80, off = j - (j / 80) * 80;
        int byte = row * APITCH + (off < 8 ? off * 16 : 7296 + (off - 8) * 16);
        *(int4v*)((char*)aA + byte) = zi;
    }
    if (h0 == 0)
        for (int j = tid; j < 528; j += 512) *(int4v*)((char*)aA + j * 16) = zi;
    if (h0 == 54)
        for (int j = tid; j < 528; j += 512) *(int4v*)((char*)aA + 3 * APITCH + j * 16) = zi;
    STAGEA(0);
    STAGEB(tap0, 0);
    asm volatile("s_waitcnt vmcnt(0) lgkmcnt(0)" ::: "memory");
    __builtin_amdgcn_sched_barrier(0);
    __builtin_amdgcn_s_barrier();

    int4v acc[3][4][2];
#pragma unroll
    for (int sp = 0; sp < 3; ++sp)
#pragma unroll
        for (int m = 0; m < 4; ++m) { acc[sp][m][0] = zi; acc[sp][m][1] = zi; }
    float v[2][4][4];
#pragma unroll
    for (int nf = 0; nf < 2; ++nf)
#pragma unroll
        for (int m = 0; m < 4; ++m)
#pragma unroll
            for (int r = 0; r < 4; ++r) v[nf][m][r] = 0.f;
    int4v a[4][2];
    LOADA(tap0);

    const int cob = (q * 32 + fr) * 128;
    const int sl0 = (fq ^ (fr & 7)) << 4;
    const int sl1 = ((4 + fq) ^ (fr & 7)) << 4;

    // ---- 36 periods ----
    int tap = tap0;
    for (int g = 0; g < 36; ++g) {
        const int t = g / 9;
        const int it = g - t * 9;             // 0..8
        const bool tend = (it == 8);
        const int ntap = (tap + 1 == 9) ? 0 : tap + 1;

        if (tend && t < 3) STAGEA(t + 1);     // A issued before B (older in queue)
        if (g < 35) STAGEB(ntap, (g + 1) & 1);
        if (g == 35) {
            asm volatile("s_waitcnt vmcnt(0)" ::: "memory");
        } else if (tend) {
            // retire only the old-B writes; leave {nA A, 6 new B} in flight
            if (tid < 448) {
                if (nA == 4) asm volatile("s_waitcnt vmcnt(10)" ::: "memory");
                else         asm volatile("s_waitcnt vmcnt(9)"  ::: "memory");
            } else {
                asm volatile("s_waitcnt vmcnt(6)" ::: "memory");
            }
        } else {
            asm volatile("s_waitcnt vmcnt(6)" ::: "memory");
        }
        __builtin_amdgcn_sched_barrier(0);
        __builtin_amdgcn_s_barrier();

        // front reads: all 12 b-frags (+ a-frags at t-start)
        const signed char* bbase = &bB[g & 1][0];
        int4v bfr[3][2][2];
#pragma unroll
        for (int sp = 0; sp < 3; ++sp) {
            const signed char* bp = bbase + sp * 16384;
            bfr[sp][0][0] = *(const int4v*)(bp + cob + sl0);
            bfr[sp][1][0] = *(const int4v*)(bp + cob + sl1);
            bfr[sp][0][1] = *(const int4v*)(bp + cob + 2048 + sl0);
            bfr[sp][1][1] = *(const int4v*)(bp + cob + 2048 + sl1);
        }
        if (it == 0 && g > 0) LOADA(tap);

        const bool dotail = !tend;
        const int ndh = ntap / 3, ndw = ntap - ndh * 3;
        const signed char* nrb = aA + (row_local + ndh) * APITCH;

        __builtin_amdgcn_s_setprio(1);
#pragma unroll
        for (int m = 0; m < 4; ++m) {
#pragma unroll
            for (int sp = 0; sp < 3; ++sp) {
                acc[sp][m][0] = __builtin_amdgcn_mfma_i32_16x16x64_i8(a[m][0], bfr[sp][0][0], acc[sp][m][0], 0, 0, 0);
                acc[sp][m][1] = __builtin_amdgcn_mfma_i32_16x16x64_i8(a[m][0], bfr[sp][0][1], acc[sp][m][1], 0, 0, 0);
            }
#pragma unroll
            for (int sp = 0; sp < 3; ++sp) {
                acc[sp][m][0] = __builtin_amdgcn_mfma_i32_16x16x64_i8(a[m][1], bfr[sp][1][0], acc[sp][m][0], 0, 0, 0);
                acc[sp][m][1] = __builtin_amdgcn_mfma_i32_16x16x64_i8(a[m][1], bfr[sp][1][1], acc[sp][m][1], 0, 0, 0);
            }
            if (dotail) {                      // a[m] free: prefetch next tap's frags
                int px1 = m * 16 + fr + ndw;
                int k7 = (px1 - 1) & 7;
                const signed char* bp2 = nrb + px1 * 128;
                a[m][0] = *(const int4v*)(bp2 + ((fq ^ k7) << 4));
                a[m][1] = *(const int4v*)(bp2 + (((4 + fq) ^ k7) << 4));
            }
        }
        __builtin_amdgcn_s_setprio(0);

        if (it == 7) {                         // next period restages aA: drain reads
            asm volatile("s_waitcnt lgkmcnt(0)" ::: "memory");
            __builtin_amdgcn_sched_barrier(0);
        }
        __builtin_amdgcn_s_barrier();

        if (tend) {
            // ---- per-t epilogue: fold + BN + PLIF (+store) ----
            if (MODE == 0) {
                signed char* S1 = (signed char*)outp;
#pragma unroll
                for (int nf = 0; nf < 2; ++nf)
#pragma unroll
                    for (int m = 0; m < 4; ++m)
#pragma unroll
                        for (int r = 0; r < 4; ++r) {
                            int px = m * 16 + fq * 4 + r;
                            float val = (float)acc[0][m][nf][r]
                                      + (float)acc[1][m][nf][r] * 0.0078125f
                                      + (float)acc[2][m][nf][r] * 6.103515625e-05f;
                            float y = fmaf(val, mulv[nf], bsv[nf]);
                            float vv = v[nf][m][r];
                            vv = vv + (y - vv) * kk;
                            bool spk = vv >= 1.f;
                            v[nf][m][r] = spk ? 0.f : vv;
                            sS[row_local * 8192 + px * 128 + q * 32 + nf * 16 + fr] = spk ? 1 : 0;
                        }
                asm volatile("s_waitcnt lgkmcnt(0)" ::: "memory");
                __builtin_amdgcn_s_barrier();
                const size_t imgb = (size_t)(t * 8 + bb) * HW;
#pragma unroll
                for (int cc = 0; cc < 2; ++cc) {
                    int chunk = tid + cc * 512;
                    int row = chunk >> 9, rem = chunk & 511;
                    int px = rem >> 3, cg = rem & 7;
                    if (px < 56) {
                        int4v v16 = *(const int4v*)(sS + row * 8192 + px * 128 + cg * 16);
                        *(int4v*)(S1 + (imgb + (size_t)(h0 + row) * 56 + px) * 128
                                     + ((cg ^ (px & 7)) << 4)) = v16;
                    }
                }
            } else {
                float* outw = (float*)outp;
#pragma unroll
                for (int nf = 0; nf < 2; ++nf) {
                    const size_t cobase = ((size_t)(t * 8 + bb) * 128 + q * 32 + nf * 16 + fr) * HW
                                        + (size_t)h * 56;
#pragma unroll
                    for (int m = 0; m < 4; ++m) {
                        int px0 = m * 16 + fq * 4;
                        float o4[4];
#pragma unroll
                        for (int r = 0; r < 4; ++r) {
                            float val = (float)acc[0][m][nf][r]
                                      + (float)acc[1][m][nf][r] * 0.0078125f
                                      + (float)acc[2][m][nf][r] * 6.103515625e-05f;
                            float y = fmaf(val, mulv[nf], bsv[nf]);
                            float vv = v[nf][m][r];
                            vv = vv + (y - vv) * kk;
                            bool spk = vv >= 1.f;
                            v[nf][m][r] = spk ? 0.f : vv;
                            o4[r] = spk ? 1.f : 0.f;
                        }
                        if (px0 < 56) {
                            float4 xv = *(const float4*)(xres + cobase + px0);
                            float4 ov = make_float4(o4[0] + xv.x, o4[1] + xv.y,
                                                    o4[2] + xv.z, o4[3] + xv.w);
                            *(float4*)(outw + cobase + px0) = ov;
                        }
                    }
                }
            }
#pragma unroll
            for (int sp = 0; sp < 3; ++sp)
#pragma unroll
                for (int m = 0; m < 4; ++m) { acc[sp][m][0] = zi; acc[sp][m][1] = zi; }
        }
        tap = ntap;
    }
#undef STAGEA
#undef STAGEB
#undef LOADA
}

// ---------------------------------------------------------------------------
extern "C" void kernel_launch(void* const* d_in, const int* in_sizes, int n_in,
                              void* d_out, int out_size, void* d_ws, size_t ws_size,
                              hipStream_t stream) {
    const float* x    = (const float*)d_in[0];
    const float* w1   = (const float*)d_in[1];
    const float* g1   = (const float*)d_in[2];
    const float* be1  = (const float*)d_in[3];
    const float* mu1  = (const float*)d_in[4];
    const float* va1  = (const float*)d_in[5];
    const float* tau1 = (const float*)d_in[6];
    const float* w2   = (const float*)d_in[7];
    const float* g2   = (const float*)d_in[8];
    const float* be2  = (const float*)d_in[9];
    const float* mu2  = (const float*)d_in[10];
    const float* va2  = (const float*)d_in[11];
    const float* tau2 = (const float*)d_in[12];
    float* out = (float*)d_out;

    char* ws = (char*)d_ws;
    signed char* Xt  = (signed char*)ws;           // i8 [NE]
    signed char* S1  = (signed char*)(ws + NE);    // i8 [NE]
    float* sv1  = (float*)(ws + 2 * NE);
    float* sv2  = sv1 + 128;
    signed char* Bs1 = (signed char*)(ws + 2 * NE + 1024);
    signed char* Bs2 = Bs1 + 27 * 16384;

    scale_k<<<128, 128, 0, stream>>>(w1, sv1);
    scale_k<<<128, 128, 0, stream>>>(w2, sv2);
    repack_k<<<36, 256, 0, stream>>>(w1, sv1, Bs1);
    repack_k<<<36, 256, 0, stream>>>(w2, sv2, Bs2);
    xpose_k<<<NIMG * 56, 256, 0, stream>>>(x, Xt);

    convplif_k<0><<<B_ * 28, 512, 0, stream>>>(Xt, Bs1, sv1, g1, be1, mu1, va1,
                                               tau1, x, (void*)S1);
    convplif_k<1><<<B_ * 28, 512, 0, stream>>>(S1, Bs2, sv2, g2, be2, mu2, va2,
                                               tau2, x, (void*)out);
}